// Round 3
// baseline (6921.575 us; speedup 1.0000x reference)
//
#include <hip/hip_runtime.h>
#include <math.h>

// Problem constants
#define D_IN   2048
#define E_NUM  64
#define NTOK   16384        // B*S = 4*4096

// Fused-MLP tiling (round-0 validated structure; accumulation upgraded to f64)
#define BM     64           // tokens per block
#define BN     256          // hidden cols per chunk
#define BK     32
#define NTHR   256
#define LDA    68           // As leading dim (words)
#define LDH    68           // hsT leading dim
#define NCHUNK (D_IN / BN)  // 8
#define NKITER (D_IN / BK)  // 64

// Output layout (floats) inside d_out:
//   weights  [16384*2] @ 0
//   indices  [16384*2] @ 32768   (stored as float(idx))
//   baseline [16384]   @ 65536
//   pg       [16384*2] @ 81920
//   scores   [16384*64]@ 114688

__global__ __launch_bounds__(NTHR, 2)
void fused_mlp_kernel(const float* __restrict__ x,
                      const float* __restrict__ W1r, const float* __restrict__ b1r,
                      const float* __restrict__ W2r, const float* __restrict__ b2r,
                      const float* __restrict__ W1b, const float* __restrict__ b1b,
                      const float* __restrict__ W2b, const float* __restrict__ b2b,
                      float* __restrict__ out_scores,    // [NTOK*64]
                      float* __restrict__ out_baseline)  // [NTOK]
{
    extern __shared__ float smem[];
    float* As  = smem;            // [BK][LDA]  x^T tile
    float* Bs  = smem + BK * LDA; // [BK][BN]   W1 tile
    float* hsT = smem;            // [BN][LDH]  gelu(h)^T overlay (after sync)

    const int tid    = threadIdx.x;
    const int isBase = blockIdx.y;          // 0: router path, 1: baseline path
    const int row0   = blockIdx.x * BM;

    const float* W1 = isBase ? W1b : W1r;
    const float* b1 = isBase ? b1b : b1r;

    // stage-1 compute mapping: 8x8 microtile
    const int ty = tid >> 5;                // 0..7 : tokens 8*ty..8*ty+7
    const int tx = tid & 31;                // cols 4*tx and 128+4*tx

    // staging mapping
    const int sm  = tid >> 3;               // 0..31 x-row
    const int skq = tid & 7;                // x col-quad
    const int bk4 = tid >> 6;               // 0..3  W1 row base (wave-uniform)
    const int bn4 = (tid & 63) * 4;         // W1 col

    // stage-2 mapping (router): 4 tokens x 4 experts per thread
    const int sy = tid >> 4;                // 0..15 tokens 4*sy..
    const int sx = tid & 15;                // experts 4*sx..
    double acc2[4][4] = {};
    // stage-2 mapping (baseline): lane-per-token, wave-per-h-range
    const int tb = tid & 63;
    const int hg = tid >> 6;                // 0..3 (wave-uniform)
    double blacc = 0.0;

    for (int ch = 0; ch < NCHUNK; ++ch) {
        const int col0 = ch * BN;
        double acc[8][8] = {};              // f64 accumulation: exact sums of f32 products

        for (int kc = 0; kc < NKITER; ++kc) {
            const int k0 = kc * BK;
            __syncthreads();  // prev-iter LDS reads done (also guards hsT overlay)

            // ---- stage x -> As (transposed)
            const float* xp = x + (size_t)(row0 + sm) * D_IN + (k0 + 4 * skq);
            float4 xv0 = *(const float4*)xp;
            float4 xv1 = *(const float4*)(xp + (size_t)32 * D_IN);
            // ---- stage W1 -> Bs (row-contiguous b128 writes, conflict-free)
            const float* wp = W1 + (size_t)(k0 + bk4) * D_IN + (col0 + bn4);
            float4 wv[8];
            #pragma unroll
            for (int j = 0; j < 8; ++j)
                wv[j] = *(const float4*)(wp + (size_t)(4 * j) * D_IN);

            As[(4 * skq + 0) * LDA + sm] = xv0.x;
            As[(4 * skq + 1) * LDA + sm] = xv0.y;
            As[(4 * skq + 2) * LDA + sm] = xv0.z;
            As[(4 * skq + 3) * LDA + sm] = xv0.w;
            As[(4 * skq + 0) * LDA + sm + 32] = xv1.x;
            As[(4 * skq + 1) * LDA + sm + 32] = xv1.y;
            As[(4 * skq + 2) * LDA + sm + 32] = xv1.z;
            As[(4 * skq + 3) * LDA + sm + 32] = xv1.w;
            #pragma unroll
            for (int j = 0; j < 8; ++j)
                *(float4*)&Bs[(bk4 + 4 * j) * BN + bn4] = wv[j];

            __syncthreads();

            // ---- 8x8 outer-product, f64 FMA (f32->f64 products are exact)
            #pragma unroll 4
            for (int kk = 0; kk < BK; ++kk) {
                float4 A0 = *(float4*)&As[kk * LDA + 8 * ty];
                float4 A1 = *(float4*)&As[kk * LDA + 8 * ty + 4];
                float4 B0 = *(float4*)&Bs[kk * BN + 4 * tx];
                float4 B1 = *(float4*)&Bs[kk * BN + 128 + 4 * tx];
                double a64[8] = {(double)A0.x, (double)A0.y, (double)A0.z, (double)A0.w,
                                 (double)A1.x, (double)A1.y, (double)A1.z, (double)A1.w};
                double b64[8] = {(double)B0.x, (double)B0.y, (double)B0.z, (double)B0.w,
                                 (double)B1.x, (double)B1.y, (double)B1.z, (double)B1.w};
                #pragma unroll
                for (int i = 0; i < 8; ++i)
                    #pragma unroll
                    for (int j = 0; j < 8; ++j)
                        acc[i][j] = fma(a64[i], b64[j], acc[i][j]);
            }
        }

        // ---- bias + exact GELU in double, write h^T (f32) into LDS overlay
        __syncthreads();
        #pragma unroll
        for (int j = 0; j < 8; ++j) {
            const int c = (j < 4) ? (4 * tx + j) : (128 + 4 * tx + (j - 4));
            const double bias = (double)b1[col0 + c];
            float h[8];
            #pragma unroll
            for (int i = 0; i < 8; ++i) {
                const double z = acc[i][j] + bias;
                h[i] = (float)(0.5 * z * (1.0 + erf(z * 0.70710678118654752440)));
            }
            *(float4*)&hsT[c * LDH + 8 * ty]     = make_float4(h[0], h[1], h[2], h[3]);
            *(float4*)&hsT[c * LDH + 8 * ty + 4] = make_float4(h[4], h[5], h[6], h[7]);
        }
        __syncthreads();

        // ---- stage-2: fold chunk into f64 register accumulators
        if (!isBase) {
            #pragma unroll 2
            for (int hq = 0; hq < BN / 4; ++hq) {
                #pragma unroll
                for (int s = 0; s < 4; ++s) {
                    const int h = 4 * hq + s;
                    float4 A  = *(float4*)&hsT[h * LDH + 4 * sy];
                    float4 Bv = *(const float4*)&W2r[(size_t)(col0 + h) * E_NUM + 4 * sx];
                    double av[4] = {(double)A.x, (double)A.y, (double)A.z, (double)A.w};
                    double bv[4] = {(double)Bv.x, (double)Bv.y, (double)Bv.z, (double)Bv.w};
                    #pragma unroll
                    for (int r = 0; r < 4; ++r)
                        #pragma unroll
                        for (int e = 0; e < 4; ++e)
                            acc2[r][e] = fma(av[r], bv[e], acc2[r][e]);
                }
            }
        } else {
            #pragma unroll 4
            for (int hh = 0; hh < 64; ++hh) {
                const int h = hg * 64 + hh;                 // wave-uniform h
                blacc = fma((double)hsT[h * LDH + tb], (double)W2b[col0 + h], blacc);
            }
        }
    }

    __syncthreads();  // last chunk's hsT reads done before smem reuse (uniform)

    if (!isBase) {
        #pragma unroll
        for (int r = 0; r < 4; ++r) {
            float4 o;
            o.x = (float)(acc2[r][0] + (double)b2r[4 * sx + 0]);
            o.y = (float)(acc2[r][1] + (double)b2r[4 * sx + 1]);
            o.z = (float)(acc2[r][2] + (double)b2r[4 * sx + 2]);
            o.w = (float)(acc2[r][3] + (double)b2r[4 * sx + 3]);
            *(float4*)&out_scores[(size_t)(row0 + 4 * sy + r) * E_NUM + 4 * sx] = o;
        }
    } else {
        double* red = (double*)smem;        // 256 doubles = 2 KB, after sync
        red[tid] = blacc;
        __syncthreads();
        if (tid < 64) {
            double bl = red[tid] + red[64 + tid] + red[128 + tid] + red[192 + tid]
                      + (double)b2b[0];
            out_baseline[row0 + tid] = (float)bl;
        }
    }
}

// One wave (64 lanes) per token; lane = expert. f64 gumbel/softmax; top-k on
// f32-rounded weights to reproduce lax.top_k tie semantics.
__global__ __launch_bounds__(256)
void softmax_topk_kernel(const float* __restrict__ scores,
                         const float* __restrict__ u,
                         const float* __restrict__ baseline,
                         float* __restrict__ out_w,
                         float* __restrict__ out_i,
                         float* __restrict__ out_pg)
{
    const int tok  = (blockIdx.x * blockDim.x + threadIdx.x) >> 6;
    const int lane = threadIdx.x & 63;

    const double s  = (double)scores[(size_t)tok * E_NUM + lane];
    const double uu = (double)u[(size_t)tok * E_NUM + lane];
    const double g  = -log(-log(uu));
    const double v  = s + g;   // TEMP = 1.0

    // softmax over the wave (f64)
    double m = v;
    #pragma unroll
    for (int off = 32; off > 0; off >>= 1)
        m = fmax(m, __shfl_xor(m, off, 64));
    const double p = exp(v - m);
    double sum = p;
    #pragma unroll
    for (int off = 32; off > 0; off >>= 1)
        sum += __shfl_xor(sum, off, 64);
    const float w = (float)(p / sum);

    // top-1: lexicographic max (value desc, index asc) — matches lax.top_k ties
    float w1 = w; int i1 = lane;
    #pragma unroll
    for (int off = 32; off > 0; off >>= 1) {
        const float ov = __shfl_xor(w1, off, 64);
        const int   oi = __shfl_xor(i1, off, 64);
        if (ov > w1 || (ov == w1 && oi < i1)) { w1 = ov; i1 = oi; }
    }
    // top-2: mask winner, reduce again (probs >= 0 so -1 is a safe sentinel)
    float w2 = (lane == i1) ? -1.0f : w; int i2 = lane;
    #pragma unroll
    for (int off = 32; off > 0; off >>= 1) {
        const float ov = __shfl_xor(w2, off, 64);
        const int   oi = __shfl_xor(i2, off, 64);
        if (ov > w2 || (ov == w2 && oi < i2)) { w2 = ov; i2 = oi; }
    }

    if (lane == 0) {
        const float bl = baseline[tok];
        out_w [(size_t)tok * 2 + 0] = w1;
        out_w [(size_t)tok * 2 + 1] = w2;
        out_i [(size_t)tok * 2 + 0] = (float)i1;
        out_i [(size_t)tok * 2 + 1] = (float)i2;
        out_pg[(size_t)tok * 2 + 0] = w1 - bl;
        out_pg[(size_t)tok * 2 + 1] = w2 - bl;
    }
}

extern "C" void kernel_launch(void* const* d_in, const int* in_sizes, int n_in,
                              void* d_out, int out_size, void* d_ws, size_t ws_size,
                              hipStream_t stream) {
    const float* x   = (const float*)d_in[0];
    const float* u   = (const float*)d_in[1];
    const float* W1r = (const float*)d_in[2];
    const float* b1r = (const float*)d_in[3];
    const float* W2r = (const float*)d_in[4];
    const float* b2r = (const float*)d_in[5];
    const float* W1b = (const float*)d_in[6];
    const float* b1b = (const float*)d_in[7];
    const float* W2b = (const float*)d_in[8];
    const float* b2b = (const float*)d_in[9];

    float* out     = (float*)d_out;
    float* out_w   = out;            // 32768
    float* out_i   = out + 32768;    // 32768
    float* out_bl  = out + 65536;    // 16384
    float* out_pg  = out + 81920;    // 32768
    float* out_sc  = out + 114688;   // 1048576

    const size_t smem_bytes = (size_t)BN * LDH * sizeof(float);  // 69632

    dim3 g1(NTOK / BM, 2);  // 256 token tiles x {router, baseline}
    fused_mlp_kernel<<<g1, NTHR, smem_bytes, stream>>>(
        x, W1r, b1r, W2r, b2r, W1b, b1b, W2b, b2b, out_sc, out_bl);

    softmax_topk_kernel<<<dim3((NTOK * 64) / 256), 256, 0, stream>>>(
        out_sc, u, out_bl, out_w, out_i, out_pg);
}

// Round 5
// 6351.299 us; speedup vs baseline: 1.0898x; 1.0898x over previous
//
#include <hip/hip_runtime.h>
#include <math.h>

// Problem constants
#define D_IN   2048
#define E_NUM  64
#define NTOK   16384        // B*S = 4*4096

// Fused-MLP tiling — round-3 numerics, pipelined staging (BK 32->16, dbuf, 1 barrier/iter)
#define BM     64           // tokens per block
#define BN     256          // hidden cols per chunk
#define BK2    16           // K-step
#define NTHR   256
#define LDA    68           // As leading dim (words)
#define BSL    256          // Bs leading dim (words)
#define LDH    68           // hsT leading dim
#define NCHUNK (D_IN / BN)  // 8
#define NK2    (D_IN / BK2) // 128

// LDS word offsets for the double-buffered staging (all under the hsT overlay)
#define AS0_OFF 0                         // [16][68]  = 1088
#define BS0_OFF 1088                      // [16][256] = 4096
#define AS1_OFF 5184
#define BS1_OFF 6272                      // end 10368 < 17408

// Output layout (floats) inside d_out:
//   weights  [16384*2] @ 0
//   indices  [16384*2] @ 32768   (stored as float(idx))
//   baseline [16384]   @ 65536
//   pg       [16384*2] @ 81920
//   scores   [16384*64]@ 114688

__global__ __launch_bounds__(NTHR, 2)
void fused_mlp_kernel(const float* __restrict__ x,
                      const float* __restrict__ W1r, const float* __restrict__ b1r,
                      const float* __restrict__ W2r, const float* __restrict__ b2r,
                      const float* __restrict__ W1b, const float* __restrict__ b1b,
                      const float* __restrict__ W2b, const float* __restrict__ b2b,
                      float* __restrict__ out_scores,    // [NTOK*64]
                      float* __restrict__ out_baseline)  // [NTOK]
{
    // hsT [256][68] = 17408 words = 69632 B overlays both staging buffers -> 2 blocks/CU.
    extern __shared__ float smem[];
    float* hsT = smem;

    const int tid    = threadIdx.x;
    const int isBase = blockIdx.y;          // 0: router path, 1: baseline path
    const int row0   = blockIdx.x * BM;

    const float* W1 = isBase ? W1b : W1r;
    const float* b1 = isBase ? b1b : b1r;

    // stage-1 compute mapping: 8x8 microtile (identical to round 3)
    const int ty = tid >> 5;                // 0..7 : tokens 8*ty..8*ty+7
    const int tx = tid & 31;                // cols 4*tx and 128+4*tx

    // staging mapping (BK2=16): x -> 1 float4/thread, W1 -> 4 float4/thread
    const int sm2  = tid >> 2;              // 0..63 x-row
    const int skq2 = tid & 3;               // x col-quad 0..3
    const int bk   = tid >> 6;              // 0..3  W1 row base (wave-uniform)
    const int bn4  = (tid & 63) * 4;        // W1 col

    // stage-2 mapping (router): 4 tokens x 4 experts per thread
    const int sy = tid >> 4;                // 0..15 tokens 4*sy..
    const int sx = tid & 15;                // experts 4*sx..
    double acc2[4][4] = {};
    // stage-2 mapping (baseline): lane-per-token, wave-per-h-range
    const int tb = tid & 63;
    const int hg = tid >> 6;                // 0..3 (wave-uniform)
    double blacc = 0.0;

    const float* xrow = x + (size_t)(row0 + sm2) * D_IN + 4 * skq2;

    for (int ch = 0; ch < NCHUNK; ++ch) {
        const int col0 = ch * BN;
        double acc[8][8] = {};              // f64 accumulation (round-3 numerics)

        // ---- prologue: stage tiles kc=0 into buf0, preload tiles kc=1 into regs
        __syncthreads();                    // prev chunk's hsT reads done (overlay)

        float4 xv = *(const float4*)(xrow + 0);
        float4 wv0, wv1, wv2, wv3;
        {
            const float* wp = W1 + (size_t)(0 + bk) * D_IN + (col0 + bn4);
            wv0 = *(const float4*)(wp + (size_t)0 * D_IN);
            wv1 = *(const float4*)(wp + (size_t)4 * D_IN);
            wv2 = *(const float4*)(wp + (size_t)8 * D_IN);
            wv3 = *(const float4*)(wp + (size_t)12 * D_IN);
        }
        {
            float* As = smem + AS0_OFF;
            float* Bs = smem + BS0_OFF;
            As[(4 * skq2 + 0) * LDA + sm2] = xv.x;
            As[(4 * skq2 + 1) * LDA + sm2] = xv.y;
            As[(4 * skq2 + 2) * LDA + sm2] = xv.z;
            As[(4 * skq2 + 3) * LDA + sm2] = xv.w;
            *(float4*)&Bs[(bk + 0)  * BSL + bn4] = wv0;
            *(float4*)&Bs[(bk + 4)  * BSL + bn4] = wv1;
            *(float4*)&Bs[(bk + 8)  * BSL + bn4] = wv2;
            *(float4*)&Bs[(bk + 12) * BSL + bn4] = wv3;
        }
        // preload tiles kc=1
        xv = *(const float4*)(xrow + BK2);
        {
            const float* wp = W1 + (size_t)(BK2 + bk) * D_IN + (col0 + bn4);
            wv0 = *(const float4*)(wp + (size_t)0 * D_IN);
            wv1 = *(const float4*)(wp + (size_t)4 * D_IN);
            wv2 = *(const float4*)(wp + (size_t)8 * D_IN);
            wv3 = *(const float4*)(wp + (size_t)12 * D_IN);
        }

        for (int kc = 0; kc < NK2; ++kc) {
            float* Asc = smem + ((kc & 1) ? AS1_OFF : AS0_OFF);
            float* Bsc = smem + ((kc & 1) ? BS1_OFF : BS0_OFF);
            float* Asn = smem + ((kc & 1) ? AS0_OFF : AS1_OFF);
            float* Bsn = smem + ((kc & 1) ? BS0_OFF : BS1_OFF);

            // One barrier per iter: separates (a) iter kc-1's reads of buf[next]
            // from this iter's writes to it, (b) writes of buf[cur] (iter kc-1)
            // from this iter's reads.
            __syncthreads();

            if (kc < NK2 - 1) {
                // ds_write tiles(kc+1) from regs (vmcnt wait hidden under prev compute)
                Asn[(4 * skq2 + 0) * LDA + sm2] = xv.x;
                Asn[(4 * skq2 + 1) * LDA + sm2] = xv.y;
                Asn[(4 * skq2 + 2) * LDA + sm2] = xv.z;
                Asn[(4 * skq2 + 3) * LDA + sm2] = xv.w;
                *(float4*)&Bsn[(bk + 0)  * BSL + bn4] = wv0;
                *(float4*)&Bsn[(bk + 4)  * BSL + bn4] = wv1;
                *(float4*)&Bsn[(bk + 8)  * BSL + bn4] = wv2;
                *(float4*)&Bsn[(bk + 12) * BSL + bn4] = wv3;
                if (kc < NK2 - 2) {
                    // issue loads for tiles(kc+2); land during compute(kc)+compute(kc+1)
                    const int k0n = (kc + 2) * BK2;
                    xv = *(const float4*)(xrow + k0n);
                    const float* wp = W1 + (size_t)(k0n + bk) * D_IN + (col0 + bn4);
                    wv0 = *(const float4*)(wp + (size_t)0 * D_IN);
                    wv1 = *(const float4*)(wp + (size_t)4 * D_IN);
                    wv2 = *(const float4*)(wp + (size_t)8 * D_IN);
                    wv3 = *(const float4*)(wp + (size_t)12 * D_IN);
                }
            }

            // ---- 8x8 outer-product, f64 FMA — k ascending, bit-identical to round 3
            #pragma unroll 8
            for (int kk = 0; kk < BK2; ++kk) {
                float4 A0 = *(float4*)&Asc[kk * LDA + 8 * ty];
                float4 A1 = *(float4*)&Asc[kk * LDA + 8 * ty + 4];
                float4 B0 = *(float4*)&Bsc[kk * BSL + 4 * tx];
                float4 B1 = *(float4*)&Bsc[kk * BSL + 128 + 4 * tx];
                double a64[8] = {(double)A0.x, (double)A0.y, (double)A0.z, (double)A0.w,
                                 (double)A1.x, (double)A1.y, (double)A1.z, (double)A1.w};
                double b64[8] = {(double)B0.x, (double)B0.y, (double)B0.z, (double)B0.w,
                                 (double)B1.x, (double)B1.y, (double)B1.z, (double)B1.w};
                #pragma unroll
                for (int i = 0; i < 8; ++i)
                    #pragma unroll
                    for (int j = 0; j < 8; ++j)
                        acc[i][j] = fma(a64[i], b64[j], acc[i][j]);
            }
        }

        // ---- bias + exact GELU in double, write h^T (f32) into LDS overlay
        __syncthreads();                    // last compute reads done; buffers dead
        #pragma unroll
        for (int j = 0; j < 8; ++j) {
            const int c = (j < 4) ? (4 * tx + j) : (128 + 4 * tx + (j - 4));
            const double bias = (double)b1[col0 + c];
            float h[8];
            #pragma unroll
            for (int i = 0; i < 8; ++i) {
                const double z = acc[i][j] + bias;
                h[i] = (float)(0.5 * z * (1.0 + erf(z * 0.70710678118654752440)));
            }
            *(float4*)&hsT[c * LDH + 8 * ty]     = make_float4(h[0], h[1], h[2], h[3]);
            *(float4*)&hsT[c * LDH + 8 * ty + 4] = make_float4(h[4], h[5], h[6], h[7]);
        }
        __syncthreads();

        // ---- stage-2: fold chunk into f64 register accumulators (unchanged)
        if (!isBase) {
            #pragma unroll 2
            for (int hq = 0; hq < BN / 4; ++hq) {
                #pragma unroll
                for (int s = 0; s < 4; ++s) {
                    const int h = 4 * hq + s;
                    float4 A  = *(float4*)&hsT[h * LDH + 4 * sy];
                    float4 Bv = *(const float4*)&W2r[(size_t)(col0 + h) * E_NUM + 4 * sx];
                    double av[4] = {(double)A.x, (double)A.y, (double)A.z, (double)A.w};
                    double bv[4] = {(double)Bv.x, (double)Bv.y, (double)Bv.z, (double)Bv.w};
                    #pragma unroll
                    for (int r = 0; r < 4; ++r)
                        #pragma unroll
                        for (int e = 0; e < 4; ++e)
                            acc2[r][e] = fma(av[r], bv[e], acc2[r][e]);
                }
            }
        } else {
            #pragma unroll 4
            for (int hh = 0; hh < 64; ++hh) {
                const int h = hg * 64 + hh;                 // wave-uniform h
                blacc = fma((double)hsT[h * LDH + tb], (double)W2b[col0 + h], blacc);
            }
        }
    }

    __syncthreads();  // last chunk's hsT reads done before smem reuse (uniform)

    if (!isBase) {
        #pragma unroll
        for (int r = 0; r < 4; ++r) {
            float4 o;
            o.x = (float)(acc2[r][0] + (double)b2r[4 * sx + 0]);
            o.y = (float)(acc2[r][1] + (double)b2r[4 * sx + 1]);
            o.z = (float)(acc2[r][2] + (double)b2r[4 * sx + 2]);
            o.w = (float)(acc2[r][3] + (double)b2r[4 * sx + 3]);
            *(float4*)&out_scores[(size_t)(row0 + 4 * sy + r) * E_NUM + 4 * sx] = o;
        }
    } else {
        double* red = (double*)smem;        // 256 doubles = 2 KB, after sync
        red[tid] = blacc;
        __syncthreads();
        if (tid < 64) {
            double bl = red[tid] + red[64 + tid] + red[128 + tid] + red[192 + tid]
                      + (double)b2b[0];
            out_baseline[row0 + tid] = (float)bl;
        }
    }
}

// One wave (64 lanes) per token; lane = expert. f64 gumbel/softmax; top-k on
// f32-rounded weights to reproduce lax.top_k tie semantics. (unchanged, passing)
__global__ __launch_bounds__(256)
void softmax_topk_kernel(const float* __restrict__ scores,
                         const float* __restrict__ u,
                         const float* __restrict__ baseline,
                         float* __restrict__ out_w,
                         float* __restrict__ out_i,
                         float* __restrict__ out_pg)
{
    const int tok  = (blockIdx.x * blockDim.x + threadIdx.x) >> 6;
    const int lane = threadIdx.x & 63;

    const double s  = (double)scores[(size_t)tok * E_NUM + lane];
    const double uu = (double)u[(size_t)tok * E_NUM + lane];
    const double g  = -log(-log(uu));
    const double v  = s + g;   // TEMP = 1.0

    // softmax over the wave (f64)
    double m = v;
    #pragma unroll
    for (int off = 32; off > 0; off >>= 1)
        m = fmax(m, __shfl_xor(m, off, 64));
    const double p = exp(v - m);
    double sum = p;
    #pragma unroll
    for (int off = 32; off > 0; off >>= 1)
        sum += __shfl_xor(sum, off, 64);
    const float w = (float)(p / sum);

    // top-1: lexicographic max (value desc, index asc) — matches lax.top_k ties
    float w1 = w; int i1 = lane;
    #pragma unroll
    for (int off = 32; off > 0; off >>= 1) {
        const float ov = __shfl_xor(w1, off, 64);
        const int   oi = __shfl_xor(i1, off, 64);
        if (ov > w1 || (ov == w1 && oi < i1)) { w1 = ov; i1 = oi; }
    }
    // top-2: mask winner, reduce again (probs >= 0 so -1 is a safe sentinel)
    float w2 = (lane == i1) ? -1.0f : w; int i2 = lane;
    #pragma unroll
    for (int off = 32; off > 0; off >>= 1) {
        const float ov = __shfl_xor(w2, off, 64);
        const int   oi = __shfl_xor(i2, off, 64);
        if (ov > w2 || (ov == w2 && oi < i2)) { w2 = ov; i2 = oi; }
    }

    if (lane == 0) {
        const float bl = baseline[tok];
        out_w [(size_t)tok * 2 + 0] = w1;
        out_w [(size_t)tok * 2 + 1] = w2;
        out_i [(size_t)tok * 2 + 0] = (float)i1;
        out_i [(size_t)tok * 2 + 1] = (float)i2;
        out_pg[(size_t)tok * 2 + 0] = w1 - bl;
        out_pg[(size_t)tok * 2 + 1] = w2 - bl;
    }
}

extern "C" void kernel_launch(void* const* d_in, const int* in_sizes, int n_in,
                              void* d_out, int out_size, void* d_ws, size_t ws_size,
                              hipStream_t stream) {
    const float* x   = (const float*)d_in[0];
    const float* u   = (const float*)d_in[1];
    const float* W1r = (const float*)d_in[2];
    const float* b1r = (const float*)d_in[3];
    const float* W2r = (const float*)d_in[4];
    const float* b2r = (const float*)d_in[5];
    const float* W1b = (const float*)d_in[6];
    const float* b1b = (const float*)d_in[7];
    const float* W2b = (const float*)d_in[8];
    const float* b2b = (const float*)d_in[9];

    float* out     = (float*)d_out;
    float* out_w   = out;            // 32768
    float* out_i   = out + 32768;    // 32768
    float* out_bl  = out + 65536;    // 16384
    float* out_pg  = out + 81920;    // 32768
    float* out_sc  = out + 114688;   // 1048576

    const size_t smem_bytes = (size_t)BN * LDH * sizeof(float);  // 69632

    dim3 g1(NTOK / BM, 2);  // 256 token tiles x {router, baseline}
    fused_mlp_kernel<<<g1, NTHR, smem_bytes, stream>>>(
        x, W1r, b1r, W2r, b2r, W1b, b1b, W2b, b2b, out_sc, out_bl);

    softmax_topk_kernel<<<dim3((NTOK * 64) / 256), 256, 0, stream>>>(
        out_sc, u, out_bl, out_w, out_i, out_pg);
}